// Round 2
// baseline (255.594 us; speedup 1.0000x reference)
//
#include <hip/hip_runtime.h>
#include <math.h>

typedef __attribute__((ext_vector_type(8))) short short8;
typedef __attribute__((ext_vector_type(4))) float float4v;

#define KDIM  512
#define NQKV  1536

__device__ __forceinline__ unsigned short f2bf(float f) {
    unsigned int u = __float_as_uint(f);
    u += 0x7FFFu + ((u >> 16) & 1u);   // round-to-nearest-even
    return (unsigned short)(u >> 16);
}
__device__ __forceinline__ float bf2f(unsigned short u) {
    return __uint_as_float(((unsigned int)u) << 16);
}

// async global->LDS DMA, 16 B per lane; LDS dest = wave-uniform base + lane*16
__device__ __forceinline__ void gl2lds16(const unsigned short* g, unsigned short* l) {
    __builtin_amdgcn_global_load_lds(
        (const __attribute__((address_space(1))) void*)g,
        (__attribute__((address_space(3))) void*)l, 16, 0, 0);
}

// ---------------- cast weights ----------------
__global__ __launch_bounds__(256) void cast_w_kernel(const float* __restrict__ wqkv,
                                                     const float* __restrict__ wproj,
                                                     unsigned short* __restrict__ wqkvb,
                                                     unsigned short* __restrict__ wprojb) {
    int tid = blockIdx.x * 256 + threadIdx.x;
    int e = tid << 2;
    if (e < NQKV * KDIM) {
        float4 v = *(const float4*)(wqkv + e);
        ushort4 o; o.x = f2bf(v.x); o.y = f2bf(v.y); o.z = f2bf(v.z); o.w = f2bf(v.w);
        *(ushort4*)(wqkvb + e) = o;
    } else {
        int e2 = e - NQKV * KDIM;
        float4 v = *(const float4*)(wproj + e2);
        ushort4 o; o.x = f2bf(v.x); o.y = f2bf(v.y); o.z = f2bf(v.z); o.w = f2bf(v.w);
        *(ushort4*)(wprojb + e2) = o;
    }
}

// ---------------- GEMM: C[M,N] = A[M,K] @ B[N,K]^T ----------------
// 128x128 tile, BK=64 (32 MFMA per barrier pair), 4 waves (2x2).
// B staged via global_load_lds width=16 into flat row-major stride-64 LDS with an
// XOR col-block swizzle applied on the GLOBAL address side (DMA LDS dest must be
// lane-contiguous): stored block p at row r holds source col-block p^(r&7).
// A path (QKV, !PROJ): fused f32->bf16 cast + roll(-32), software-pipelined by
// one K-step: ra[8] holds A(k)'s f32 loads (issued last iter, drained at the
// previous barrier -> zero-wait cvt), then ra is re-issued for A(k+1) AFTER the
// cvt reads it (WAR-safe). The barrier's vmcnt(0) drain covers B-DMA and the
// A-prefetch together, so A latency hides fully under B latency.
// XCD-aware bijective swizzle: nwg%8==0 for both shapes; blocks sharing an
// A-panel (same bm) land on the same XCD -> A fetched ~once from HBM.
template<int N, bool PROJ>
__global__ __launch_bounds__(256, 2) void gemm_kernel(
        const unsigned short* __restrict__ A,   // bf16 A (PROJ path)
        const float* __restrict__ Ax,           // f32 x (QKV path, roll fused)
        const unsigned short* __restrict__ B,
        unsigned short* __restrict__ Cb,
        float* __restrict__ Cf,
        const float* __restrict__ bias) {
    __shared__ __align__(16) unsigned short As[128 * 64];
    __shared__ __align__(16) unsigned short Bs[128 * 64];
    constexpr int GX  = N / 128;         // blocks along n: 12 (QKV) or 4 (proj)
    constexpr int PER = (GX * 256) / 8;  // blocks per XCD (exact: nwg % 8 == 0)
    const int wgid = blockIdx.y * GX + blockIdx.x;          // dispatch-linear
    const int swz  = (wgid & 7) * PER + (wgid >> 3);        // bijective chunking
    const int bm = swz / GX;
    const int bn = swz % GX;

    const int tid = threadIdx.x;
    const int wave = tid >> 6, lane = tid & 63;
    const int quad = lane >> 4, l16 = lane & 15;
    const int wm = (wave >> 1) * 64, wn = (wave & 1) * 64;
    // staging geometry: chunk = 8 rows x 64 cols = 1 KB. Lane covers row
    // chunk*8+(lane>>3), stored col-block lane&7, holding source col-block
    // (lane&7)^(row&7).
    const int srow = lane >> 3;                  // 0..7 within chunk
    const int scol = ((lane & 7) ^ srow) * 8;    // swizzled source column

    float4v acc[4][4] = {};

    const unsigned short* Bbase = B + (size_t)(bn * 128) * KDIM;
    const unsigned short* Abase = PROJ ? (A + (size_t)(bm * 128) * KDIM) : nullptr;

    // QKV path: per-chunk source row pointer in x, with roll(-32) fused
    const float* arow[4];
    float4 ra[8];                // A(k) staging regs, pipelined one K-step ahead
    if (!PROJ) {
        #pragma unroll
        for (int j = 0; j < 4; j++) {
            int chunk = j * 4 + wave;
            int t = bm * 128 + chunk * 8 + srow;       // token row (shifted order)
            int b = t >> 12, n = t & 4095;
            int src = (b << 12) | ((n + 32) & 4095);   // roll(x, -32)
            arow[j] = Ax + (((size_t)src) << 9) + scol;
        }
        // prologue: issue all 8 loads for k0=0 back-to-back (no use in between)
        #pragma unroll
        for (int j = 0; j < 4; j++) {
            ra[2 * j]     = *(const float4*)(arow[j]);
            ra[2 * j + 1] = *(const float4*)(arow[j] + 4);
        }
    }

    #pragma unroll
    for (int k0i = 0; k0i < 8; k0i++) {
        const int k0 = k0i * 64;
        // ---- stage phase ----
        // 1) fire the DMAs first (latency starts immediately)
        #pragma unroll
        for (int j = 0; j < 4; j++) {
            int chunk = j * 4 + wave;               // 0..15
            int row = chunk * 8 + srow;             // 0..127
            if (PROJ)
                gl2lds16(Abase + (size_t)row * KDIM + k0 + scol, As + chunk * 512);
            gl2lds16(Bbase + (size_t)row * KDIM + k0 + scol, Bs + chunk * 512);
        }
        if (!PROJ) {
            // 2) cvt + ds_write A(k) from ra (loads complete: drained at prev barrier)
            #pragma unroll
            for (int j = 0; j < 4; j++) {
                int chunk = j * 4 + wave;
                float4 v0 = ra[2 * j], v1 = ra[2 * j + 1];
                short8 a8;
                a8[0] = (short)f2bf(v0.x); a8[1] = (short)f2bf(v0.y);
                a8[2] = (short)f2bf(v0.z); a8[3] = (short)f2bf(v0.w);
                a8[4] = (short)f2bf(v1.x); a8[5] = (short)f2bf(v1.y);
                a8[6] = (short)f2bf(v1.z); a8[7] = (short)f2bf(v1.w);
                *(short8*)(As + chunk * 512 + lane * 8) = a8;   // same swizzled slot
            }
            // 3) re-issue ra with A(k+1) (WAR after cvt); drains at the barrier
            //    below together with the B DMAs -> latency fully overlapped
            if (k0i < 7) {
                #pragma unroll
                for (int j = 0; j < 4; j++) {
                    ra[2 * j]     = *(const float4*)(arow[j] + k0 + 64);
                    ra[2 * j + 1] = *(const float4*)(arow[j] + k0 + 64 + 4);
                }
            }
        }
        __syncthreads();
        // ---- compute phase ----
        #pragma unroll
        for (int ki = 0; ki < 2; ki++) {
            short8 af[4], bf[4];
            #pragma unroll
            for (int mi = 0; mi < 4; mi++) {
                int r = wm + mi * 16 + l16;
                int blk = (ki * 4 + quad) ^ (l16 & 7);
                af[mi] = *(const short8*)(As + r * 64 + blk * 8);
            }
            #pragma unroll
            for (int ni = 0; ni < 4; ni++) {
                int r = wn + ni * 16 + l16;
                int blk = (ki * 4 + quad) ^ (l16 & 7);
                bf[ni] = *(const short8*)(Bs + r * 64 + blk * 8);
            }
            #pragma unroll
            for (int mi = 0; mi < 4; mi++)
                #pragma unroll
                for (int ni = 0; ni < 4; ni++)
                    acc[mi][ni] = __builtin_amdgcn_mfma_f32_16x16x32_bf16(
                        af[mi], bf[ni], acc[mi][ni], 0, 0, 0);
        }
        __syncthreads();
    }

    #pragma unroll
    for (int mi = 0; mi < 4; mi++) {
        #pragma unroll
        for (int r = 0; r < 4; r++) {
            int m = bm * 128 + wm + mi * 16 + quad * 4 + r;
            if (!PROJ) {
                #pragma unroll
                for (int ni = 0; ni < 4; ni++) {
                    int n = bn * 128 + wn + ni * 16 + l16;
                    Cb[(size_t)m * N + n] = f2bf(acc[mi][ni][r]);
                }
            } else {
                int b = m >> 12, p = m & 4095;
                int nrow = (p + 32) & 4095;      // roll(out, +32)
                float* orow = Cf + (((size_t)((b << 12) | nrow)) << 9);
                #pragma unroll
                for (int ni = 0; ni < 4; ni++) {
                    int n = bn * 128 + wn + ni * 16 + l16;
                    orow[n] = acc[mi][ni][r] + bias[n];
                }
            }
        }
    }
}

// ---------------- attention: 8x8 attention OVER HEADS per token ----------------
// einsum('bwhd,bwgd->bwhg'): per (window,position) token, S[h][g] = Q_h . K_g,
// softmax over g (scale 0.125), O[h] = sum_g P[h][g] V[g].
// One thread per (token, head); block = 128 threads = 16 tokens x 8 heads.
// Only K,V staged in LDS (padded stride -> conflict-free); Q loaded straight
// to registers from global, issued before staging so the loads overlap.
#define TPB_TOK 16
#define KV_STRIDE 1032   // 1024 + 8: token stride = 2064 B = 516 dw = 4 banks
__global__ __launch_bounds__(128) void attn_kernel(const unsigned short* __restrict__ qkvb,
                                                   unsigned short* __restrict__ aob) {
    __shared__ __align__(16) unsigned short smem[TPB_TOK * KV_STRIDE];
    const int tid = threadIdx.x;
    const int t0 = blockIdx.x * TPB_TOK;
    const int tok = tid >> 3, h = tid & 7;
    const int t = t0 + tok;

    // Q[h][0..63] global loads issue first (overlap with K/V staging)
    short8 qs[8];
    {
        const unsigned short* qsrc = qkvb + (size_t)t * NQKV + h * 64;
        #pragma unroll
        for (int dc = 0; dc < 8; dc++)
            qs[dc] = *(const short8*)(qsrc + dc * 8);
    }

    // stage K,V (rows of 1024 bf16 per token) into LDS, coalesced short8
    {
        int r = tid >> 3, cb = (tid & 7) * 8;
        const unsigned short* src = qkvb + (size_t)(t0 + r) * NQKV + 512;
        unsigned short* dst = smem + r * KV_STRIDE;
        #pragma unroll
        for (int p = 0; p < 16; p++) {
            int c = cb + p * 64;
            *(short8*)(dst + c) = *(const short8*)(src + c);
        }
    }
    __syncthreads();

    const unsigned short* row = smem + tok * KV_STRIDE;

    float qv[64];
    #pragma unroll
    for (int dc = 0; dc < 8; dc++)
        #pragma unroll
        for (int j = 0; j < 8; j++)
            qv[dc * 8 + j] = bf2f((unsigned short)qs[dc][j]);

    // S[g] = Q_h . K_g  (K reads h-independent -> LDS broadcast across 8 lanes)
    float s[8];
    #pragma unroll
    for (int g = 0; g < 8; g++) {
        float acc = 0.f;
        #pragma unroll
        for (int dc = 0; dc < 8; dc++) {
            short8 ks = *(const short8*)(row + g * 64 + dc * 8);
            #pragma unroll
            for (int j = 0; j < 8; j++)
                acc += qv[dc * 8 + j] * bf2f((unsigned short)ks[j]);
        }
        s[g] = acc;
    }

    float mx = s[0];
    #pragma unroll
    for (int g = 1; g < 8; g++) mx = fmaxf(mx, s[g]);
    float p[8], sum = 0.f;
    #pragma unroll
    for (int g = 0; g < 8; g++) { p[g] = __expf((s[g] - mx) * 0.125f); sum += p[g]; }
    float inv = 1.f / sum;
    #pragma unroll
    for (int g = 0; g < 8; g++) p[g] *= inv;

    float o[64];
    #pragma unroll
    for (int j = 0; j < 64; j++) o[j] = 0.f;
    #pragma unroll
    for (int g = 0; g < 8; g++) {
        #pragma unroll
        for (int dc = 0; dc < 8; dc++) {
            short8 vs = *(const short8*)(row + 512 + g * 64 + dc * 8);
            #pragma unroll
            for (int j = 0; j < 8; j++)
                o[dc * 8 + j] += p[g] * bf2f((unsigned short)vs[j]);
        }
    }

    // scrambled write replicating transpose(0,2,1,3).reshape:
    // proj-in row = win*64 + h*8 + w/8 ; col = (w%8)*64 + d
    int win = t >> 6, w = t & 63;
    unsigned short* dst = aob + (size_t)(win * 64 + h * 8 + (w >> 3)) * 512 + (w & 7) * 64;
    #pragma unroll
    for (int dc = 0; dc < 16; dc++) {
        ushort4 ov;
        ov.x = f2bf(o[dc * 4 + 0]); ov.y = f2bf(o[dc * 4 + 1]);
        ov.z = f2bf(o[dc * 4 + 2]); ov.w = f2bf(o[dc * 4 + 3]);
        *(ushort4*)(dst + dc * 4) = ov;
    }
}

extern "C" void kernel_launch(void* const* d_in, const int* in_sizes, int n_in,
                              void* d_out, int out_size, void* d_ws, size_t ws_size,
                              hipStream_t stream) {
    const float* x      = (const float*)d_in[0];
    const float* w_qkv  = (const float*)d_in[1];
    const float* w_proj = (const float*)d_in[2];
    const float* b_proj = (const float*)d_in[3];
    float* out = (float*)d_out;

    char* ws = (char*)d_ws;
    unsigned short* wqkvb  = (unsigned short*)(ws + 33554432);      // 1.5 MB
    unsigned short* wprojb = (unsigned short*)(ws + 35127296);      // 0.5 MB
    unsigned short* qkvb   = (unsigned short*)(ws + 35651584);      // 96 MB
    unsigned short* aob    = (unsigned short*)(ws + 136314880);     // 32 MB

    cast_w_kernel<<<1024, 256, 0, stream>>>(w_qkv, w_proj, wqkvb, wprojb);
    gemm_kernel<NQKV, false><<<dim3(12, 256), 256, 0, stream>>>(nullptr, x, wqkvb, qkvb, nullptr, nullptr);
    attn_kernel<<<2048, 128, 0, stream>>>(qkvb, aob);
    gemm_kernel<512, true><<<dim3(4, 256), 256, 0, stream>>>(aob, nullptr, wprojb, nullptr, out, b_proj);
}

// Round 4
// 241.860 us; speedup vs baseline: 1.0568x; 1.0568x over previous
//
#include <hip/hip_runtime.h>
#include <math.h>

typedef __attribute__((ext_vector_type(8))) short short8;
typedef __attribute__((ext_vector_type(4))) float float4v;

#define KDIM  512
#define NQKV  1536

__device__ __forceinline__ unsigned short f2bf(float f) {
    unsigned int u = __float_as_uint(f);
    u += 0x7FFFu + ((u >> 16) & 1u);   // round-to-nearest-even
    return (unsigned short)(u >> 16);
}
__device__ __forceinline__ float bf2f(unsigned short u) {
    return __uint_as_float(((unsigned int)u) << 16);
}

// async global->LDS DMA, 16 B per lane; LDS dest = wave-uniform base + lane*16
__device__ __forceinline__ void gl2lds16(const unsigned short* g, unsigned short* l) {
    __builtin_amdgcn_global_load_lds(
        (const __attribute__((address_space(1))) void*)g,
        (__attribute__((address_space(3))) void*)l, 16, 0, 0);
}

// ---------------- fused cast: x (with roll -32) + both weight matrices ----------
// blocks [0, 16384): x cast+roll ; blocks [16384, 17408): w_qkv / w_proj cast
__global__ __launch_bounds__(256) void cast_all_kernel(const float* __restrict__ x,
                                                       const float* __restrict__ wqkv,
                                                       const float* __restrict__ wproj,
                                                       unsigned short* __restrict__ xb,
                                                       unsigned short* __restrict__ wqkvb,
                                                       unsigned short* __restrict__ wprojb) {
    if (blockIdx.x < 16384) {
        int tid = blockIdx.x * 256 + threadIdx.x;
        int t = tid >> 7;               // token row 0..32767 (shifted order)
        int c = (tid & 127) << 2;
        int b = t >> 12, n = t & 4095;
        int src = (b << 12) | ((n + 32) & 4095);    // roll(x, -32)
        float4 v = *(const float4*)(x + (((size_t)src) << 9) + c);
        ushort4 o;
        o.x = f2bf(v.x); o.y = f2bf(v.y); o.z = f2bf(v.z); o.w = f2bf(v.w);
        *(ushort4*)(xb + (((size_t)t) << 9) + c) = o;
    } else {
        int tid = (blockIdx.x - 16384) * 256 + threadIdx.x;
        int e = tid << 2;
        if (e < NQKV * KDIM) {
            float4 v = *(const float4*)(wqkv + e);
            ushort4 o; o.x = f2bf(v.x); o.y = f2bf(v.y); o.z = f2bf(v.z); o.w = f2bf(v.w);
            *(ushort4*)(wqkvb + e) = o;
        } else {
            int e2 = e - NQKV * KDIM;
            float4 v = *(const float4*)(wproj + e2);
            ushort4 o; o.x = f2bf(v.x); o.y = f2bf(v.y); o.z = f2bf(v.z); o.w = f2bf(v.w);
            *(ushort4*)(wprojb + e2) = o;
        }
    }
}

// ---------------- GEMM: C[M,N] = A[M,K] @ B[N,K]^T ----------------
// 128x128 tile, BK=64 (32 MFMA per barrier pair), 4 waves (2x2).
// Staging via global_load_lds width=16 into flat row-major stride-64 LDS with an
// XOR col-block swizzle (applied on the GLOBAL address side, since the DMA's LDS
// destination must be lane-contiguous): stored block p at row r holds source
// col-block p^(r&7). Fragment ds_read_b128 then hits 8 distinct bank groups.
// NOTE: reg-staged A (fused f32 cast) was tried and is a measured LOSS (103 vs
// 72 us): mixing reg-loads with DMA defeats the vmcnt scheduling (cf. m151:
// reg-staging 646 TF vs gload_lds 874 TF). Keep BOTH operands on pure DMA.
// XCD-aware bijective swizzle: nwg%8==0 for both shapes; blocks sharing an
// A-panel (same bm) land on the same XCD -> A fetched ~once from HBM
// (measured: FETCH 135 MB -> 44 MB on the QKV gemm).
template<int N, bool PROJ>
__global__ __launch_bounds__(256, 2) void gemm_kernel(
        const unsigned short* __restrict__ A,
        const unsigned short* __restrict__ B,
        unsigned short* __restrict__ Cb,
        float* __restrict__ Cf,
        const float* __restrict__ bias) {
    __shared__ __align__(16) unsigned short As[128 * 64];
    __shared__ __align__(16) unsigned short Bs[128 * 64];
    constexpr int GX  = N / 128;         // blocks along n: 12 (QKV) or 4 (proj)
    constexpr int PER = (GX * 256) / 8;  // blocks per XCD (exact: nwg % 8 == 0)
    const int wgid = blockIdx.y * GX + blockIdx.x;          // dispatch-linear
    const int swz  = (wgid & 7) * PER + (wgid >> 3);        // bijective chunking
    const int bm = swz / GX;
    const int bn = swz % GX;

    const int tid = threadIdx.x;
    const int wave = tid >> 6, lane = tid & 63;
    const int quad = lane >> 4, l16 = lane & 15;
    const int wm = (wave >> 1) * 64, wn = (wave & 1) * 64;
    // DMA: chunk = 8 rows x 64 cols = 1 KB. Lane covers row chunk*8+(lane>>3),
    // stored col-block lane&7, which must hold source col-block (lane&7)^(row&7).
    const int srow = lane >> 3;                  // 0..7 within chunk
    const int scol = ((lane & 7) ^ srow) * 8;    // swizzled source column

    float4v acc[4][4] = {};

    const unsigned short* Abase = A + (size_t)(bm * 128) * KDIM;
    const unsigned short* Bbase = B + (size_t)(bn * 128) * KDIM;

    for (int k0 = 0; k0 < KDIM; k0 += 64) {
        #pragma unroll
        for (int j = 0; j < 4; j++) {
            int chunk = j * 4 + wave;               // 0..15
            int row = chunk * 8 + srow;             // 0..127
            gl2lds16(Abase + (size_t)row * KDIM + k0 + scol, As + chunk * 512);
            gl2lds16(Bbase + (size_t)row * KDIM + k0 + scol, Bs + chunk * 512);
        }
        __syncthreads();
        #pragma unroll
        for (int ki = 0; ki < 2; ki++) {
            short8 af[4], bf[4];
            #pragma unroll
            for (int mi = 0; mi < 4; mi++) {
                int r = wm + mi * 16 + l16;
                int blk = (ki * 4 + quad) ^ (l16 & 7);
                af[mi] = *(const short8*)(As + r * 64 + blk * 8);
            }
            #pragma unroll
            for (int ni = 0; ni < 4; ni++) {
                int r = wn + ni * 16 + l16;
                int blk = (ki * 4 + quad) ^ (l16 & 7);
                bf[ni] = *(const short8*)(Bs + r * 64 + blk * 8);
            }
            #pragma unroll
            for (int mi = 0; mi < 4; mi++)
                #pragma unroll
                for (int ni = 0; ni < 4; ni++)
                    acc[mi][ni] = __builtin_amdgcn_mfma_f32_16x16x32_bf16(
                        af[mi], bf[ni], acc[mi][ni], 0, 0, 0);
        }
        __syncthreads();
    }

    #pragma unroll
    for (int mi = 0; mi < 4; mi++) {
        #pragma unroll
        for (int r = 0; r < 4; r++) {
            int m = bm * 128 + wm + mi * 16 + quad * 4 + r;
            if (!PROJ) {
                #pragma unroll
                for (int ni = 0; ni < 4; ni++) {
                    int n = bn * 128 + wn + ni * 16 + l16;
                    Cb[(size_t)m * N + n] = f2bf(acc[mi][ni][r]);
                }
            } else {
                int b = m >> 12, p = m & 4095;
                int nrow = (p + 32) & 4095;      // roll(out, +32)
                float* orow = Cf + (((size_t)((b << 12) | nrow)) << 9);
                #pragma unroll
                for (int ni = 0; ni < 4; ni++) {
                    int n = bn * 128 + wn + ni * 16 + l16;
                    orow[n] = acc[mi][ni][r] + bias[n];
                }
            }
        }
    }
}

// ---------------- attention: 8x8 attention OVER HEADS per token ----------------
// einsum('bwhd,bwgd->bwhg'): per (window,position) token, S[h][g] = Q_h . K_g,
// softmax over g (scale 0.125), O[h] = sum_g P[h][g] V[g].
// One thread per (token, head); block = 128 threads = 16 tokens x 8 heads.
// Only K,V staged in LDS (padded stride -> conflict-free); Q loaded straight
// to registers from global, issued before staging so the loads overlap.
#define TPB_TOK 16
#define KV_STRIDE 1032   // 1024 + 8: token stride = 2064 B = 516 dw = 4 banks
__global__ __launch_bounds__(128) void attn_kernel(const unsigned short* __restrict__ qkvb,
                                                   unsigned short* __restrict__ aob) {
    __shared__ __align__(16) unsigned short smem[TPB_TOK * KV_STRIDE];
    const int tid = threadIdx.x;
    const int t0 = blockIdx.x * TPB_TOK;
    const int tok = tid >> 3, h = tid & 7;
    const int t = t0 + tok;

    // Q[h][0..63] global loads issue first (overlap with K/V staging)
    short8 qs[8];
    {
        const unsigned short* qsrc = qkvb + (size_t)t * NQKV + h * 64;
        #pragma unroll
        for (int dc = 0; dc < 8; dc++)
            qs[dc] = *(const short8*)(qsrc + dc * 8);
    }

    // stage K,V (rows of 1024 bf16 per token) into LDS, coalesced short8
    {
        int r = tid >> 3, cb = (tid & 7) * 8;
        const unsigned short* src = qkvb + (size_t)(t0 + r) * NQKV + 512;
        unsigned short* dst = smem + r * KV_STRIDE;
        #pragma unroll
        for (int p = 0; p < 16; p++) {
            int c = cb + p * 64;
            *(short8*)(dst + c) = *(const short8*)(src + c);
        }
    }
    __syncthreads();

    const unsigned short* row = smem + tok * KV_STRIDE;

    float qv[64];
    #pragma unroll
    for (int dc = 0; dc < 8; dc++)
        #pragma unroll
        for (int j = 0; j < 8; j++)
            qv[dc * 8 + j] = bf2f((unsigned short)qs[dc][j]);

    // S[g] = Q_h . K_g  (K reads h-independent -> LDS broadcast across 8 lanes)
    float s[8];
    #pragma unroll
    for (int g = 0; g < 8; g++) {
        float acc = 0.f;
        #pragma unroll
        for (int dc = 0; dc < 8; dc++) {
            short8 ks = *(const short8*)(row + g * 64 + dc * 8);
            #pragma unroll
            for (int j = 0; j < 8; j++)
                acc += qv[dc * 8 + j] * bf2f((unsigned short)ks[j]);
        }
        s[g] = acc;
    }

    float mx = s[0];
    #pragma unroll
    for (int g = 1; g < 8; g++) mx = fmaxf(mx, s[g]);
    float p[8], sum = 0.f;
    #pragma unroll
    for (int g = 0; g < 8; g++) { p[g] = __expf((s[g] - mx) * 0.125f); sum += p[g]; }
    float inv = 1.f / sum;
    #pragma unroll
    for (int g = 0; g < 8; g++) p[g] *= inv;

    float o[64];
    #pragma unroll
    for (int j = 0; j < 64; j++) o[j] = 0.f;
    #pragma unroll
    for (int g = 0; g < 8; g++) {
        #pragma unroll
        for (int dc = 0; dc < 8; dc++) {
            short8 vs = *(const short8*)(row + 512 + g * 64 + dc * 8);
            #pragma unroll
            for (int j = 0; j < 8; j++)
                o[dc * 8 + j] += p[g] * bf2f((unsigned short)vs[j]);
        }
    }

    // scrambled write replicating transpose(0,2,1,3).reshape:
    // proj-in row = win*64 + h*8 + w/8 ; col = (w%8)*64 + d
    int win = t >> 6, w = t & 63;
    unsigned short* dst = aob + (size_t)(win * 64 + h * 8 + (w >> 3)) * 512 + (w & 7) * 64;
    #pragma unroll
    for (int dc = 0; dc < 16; dc++) {
        ushort4 ov;
        ov.x = f2bf(o[dc * 4 + 0]); ov.y = f2bf(o[dc * 4 + 1]);
        ov.z = f2bf(o[dc * 4 + 2]); ov.w = f2bf(o[dc * 4 + 3]);
        *(ushort4*)(dst + dc * 4) = ov;
    }
}

extern "C" void kernel_launch(void* const* d_in, const int* in_sizes, int n_in,
                              void* d_out, int out_size, void* d_ws, size_t ws_size,
                              hipStream_t stream) {
    const float* x      = (const float*)d_in[0];
    const float* w_qkv  = (const float*)d_in[1];
    const float* w_proj = (const float*)d_in[2];
    const float* b_proj = (const float*)d_in[3];
    float* out = (float*)d_out;

    char* ws = (char*)d_ws;
    unsigned short* xb     = (unsigned short*)(ws);                 // 32 MB
    unsigned short* wqkvb  = (unsigned short*)(ws + 33554432);      // 1.5 MB
    unsigned short* wprojb = (unsigned short*)(ws + 35127296);      // 0.5 MB
    unsigned short* qkvb   = (unsigned short*)(ws + 35651584);      // 96 MB
    unsigned short* aob    = (unsigned short*)(ws + 136314880);     // 32 MB

    cast_all_kernel<<<17408, 256, 0, stream>>>(x, w_qkv, w_proj, xb, wqkvb, wprojb);
    gemm_kernel<NQKV, false><<<dim3(12, 256), 256, 0, stream>>>(xb, wqkvb, qkvb, nullptr, nullptr);
    attn_kernel<<<2048, 128, 0, stream>>>(qkvb, aob);
    gemm_kernel<512, true><<<dim3(4, 256), 256, 0, stream>>>(aob, wprojb, nullptr, out, b_proj);
}